// Round 1
// baseline (43818.875 us; speedup 1.0000x reference)
//
#include <hip/hip_runtime.h>
#include <math.h>

// Problem constants
constexpr int B_ = 2, S_ = 1024, D_ = 2048, H_ = 16;
constexpr int NOPE_ = 128, ROPE_ = 64, VD_ = 128, KVR_ = 512, QLR_ = 1536;
constexpr int NE_ = 16, MI_ = 1408, SMI_ = 2816;
constexpr int QKD_ = NOPE_ + ROPE_;            // 192
constexpr int T_ = B_ * S_;                    // 2048
constexpr float SCALE_ = 0.07216878364870322f; // 192^-0.5
constexpr float EPS_ = 1e-3f;

// ---------------------------------------------------------------------------
// Generic tiled fp32 GEMM: C[M,N] = A[M,K] @ W^T + bias + residual
// W layout: w_kn==0 -> W[N,K] row-major (ld=ldw over K)
//           w_kn==1 -> W[K,N] row-major (ld=ldw over N)   (i.e. plain A@W)
// Batched via blockIdx.z with element strides. All dims divide tile sizes
// (M%64==0, N%64==0, K%16==0 for every call below) -> no bounds checks.
// ---------------------------------------------------------------------------
__global__ __launch_bounds__(256) void gemm_kernel(
    const float* __restrict__ A, int lda, long strideA,
    const float* __restrict__ W, int ldw, long strideW, int w_kn,
    const float* __restrict__ bias, long strideBias,
    const float* __restrict__ res, int ldr, long strideRes,
    float* __restrict__ C, int ldc, long strideC,
    int M, int N, int K)
{
    (void)M;
    const int bz = blockIdx.z;
    A += (long)bz * strideA;
    W += (long)bz * strideW;
    C += (long)bz * strideC;
    if (bias) bias += (long)bz * strideBias;
    if (res)  res  += (long)bz * strideRes;

    __shared__ float As[16][68];
    __shared__ float Ws[16][68];

    const int m0 = blockIdx.y * 64;
    const int n0 = blockIdx.x * 64;
    const int tid = threadIdx.x;
    const int tx = tid & 15;   // 0..15 -> N micro
    const int ty = tid >> 4;   // 0..15 -> M micro

    float acc[4][4] = {};

    for (int kt = 0; kt < K; kt += 16) {
        #pragma unroll
        for (int i = 0; i < 4; i++) {
            int p = tid + i * 256;
            int r = p >> 4, kk = p & 15;
            As[kk][r] = A[(long)(m0 + r) * lda + (kt + kk)];
        }
        if (w_kn) {
            #pragma unroll
            for (int i = 0; i < 4; i++) {
                int p = tid + i * 256;
                int kk = p >> 6, n = p & 63;
                Ws[kk][n] = W[(long)(kt + kk) * ldw + (n0 + n)];
            }
        } else {
            #pragma unroll
            for (int i = 0; i < 4; i++) {
                int p = tid + i * 256;
                int n = p >> 4, kk = p & 15;
                Ws[kk][n] = W[(long)(n0 + n) * ldw + (kt + kk)];
            }
        }
        __syncthreads();
        #pragma unroll
        for (int kk = 0; kk < 16; kk++) {
            float a[4], b[4];
            #pragma unroll
            for (int i = 0; i < 4; i++) a[i] = As[kk][ty * 4 + i];
            #pragma unroll
            for (int j = 0; j < 4; j++) b[j] = Ws[kk][tx * 4 + j];
            #pragma unroll
            for (int i = 0; i < 4; i++)
                #pragma unroll
                for (int j = 0; j < 4; j++)
                    acc[i][j] += a[i] * b[j];
        }
        __syncthreads();
    }

    #pragma unroll
    for (int i = 0; i < 4; i++) {
        int m = m0 + ty * 4 + i;
        #pragma unroll
        for (int j = 0; j < 4; j++) {
            int n = n0 + tx * 4 + j;
            float v = acc[i][j];
            if (bias) v += bias[n];
            if (res)  v += res[(long)m * ldr + n];
            C[(long)m * ldc + n] = v;
        }
    }
}

// ---------------------------------------------------------------------------
// RMSNorm over rows: out = w * x * rsqrt(mean(x^2)+eps). In-place safe.
// ---------------------------------------------------------------------------
__global__ __launch_bounds__(256) void rms_kernel(
    const float* __restrict__ in, float* __restrict__ out,
    const float* __restrict__ w, int N, int in_stride, int out_stride)
{
    const int row = blockIdx.x;
    const float* x = in + (long)row * in_stride;
    float* y = out + (long)row * out_stride;
    __shared__ float red[256];
    const int tid = threadIdx.x;
    float s = 0.f;
    for (int i = tid; i < N; i += 256) { float v = x[i]; s += v * v; }
    red[tid] = s; __syncthreads();
    for (int st = 128; st > 0; st >>= 1) {
        if (tid < st) red[tid] += red[tid + st];
        __syncthreads();
    }
    const float scale = rsqrtf(red[0] / (float)N + EPS_);
    for (int i = tid; i < N; i += 256) y[i] = w[i] * x[i] * scale;
}

// ---------------------------------------------------------------------------
// Interleaved RoPE, in place. pos = token % S_.
// ---------------------------------------------------------------------------
__global__ void rope_kernel(float* __restrict__ p,
                            const float* __restrict__ cosb,
                            const float* __restrict__ sinb,
                            int nheads, int row_stride, int head_stride,
                            int off, int total)
{
    int i = blockIdx.x * 256 + threadIdx.x;
    if (i >= total) return;
    int pair = i & 31;
    int rem = i >> 5;
    int h = rem % nheads;
    int t = rem / nheads;
    int s = t % S_;
    float c = cosb[s * 32 + pair], sn = sinb[s * 32 + pair];
    float* base = p + (long)t * row_stride + (long)h * head_stride + off + pair * 2;
    float x0 = base[0], x1 = base[1];
    base[0] = x0 * c - x1 * sn;
    base[1] = x0 * sn + x1 * c;
}

// ---------------------------------------------------------------------------
// Attention: one block per (s, h, b). q_abs row in, o row out (same buffer).
// kvf rows: [kv_n(512) | k_pe(64)], stride 576. Full (non-causal) softmax.
// ---------------------------------------------------------------------------
__global__ __launch_bounds__(256) void attn_kernel(
    const float* __restrict__ q,    // [T, H, 192]
    const float* __restrict__ kvf,  // [T, 576]
    float* __restrict__ qabs_o)     // [T, H, 512] (in: q_abs, out: o)
{
    const int s = blockIdx.x, h = blockIdx.y, b = blockIdx.z;
    const long row = (long)(b * S_ + s) * H_ + h;
    const int t0 = b * S_;

    __shared__ float qa_l[512];
    __shared__ float qp_l[64];
    __shared__ float sc[1024];
    __shared__ float red[256];

    const int tid = threadIdx.x;
    const float* qabs_row = qabs_o + row * 512;
    for (int c = tid; c < 512; c += 256) qa_l[c] = qabs_row[c];
    const float* q_row = q + row * 192 + 128;
    if (tid < 64) qp_l[tid] = q_row[tid];
    __syncthreads();

    for (int t = tid; t < S_; t += 256) {
        const float4* kv4 = (const float4*)(kvf + (long)(t0 + t) * 576);
        float acc = 0.f;
        #pragma unroll 4
        for (int c = 0; c < 128; c++) {
            float4 k = kv4[c];
            acc += qa_l[c * 4 + 0] * k.x + qa_l[c * 4 + 1] * k.y +
                   qa_l[c * 4 + 2] * k.z + qa_l[c * 4 + 3] * k.w;
        }
        #pragma unroll 4
        for (int r = 0; r < 16; r++) {
            float4 k = kv4[128 + r];
            acc += qp_l[r * 4 + 0] * k.x + qp_l[r * 4 + 1] * k.y +
                   qp_l[r * 4 + 2] * k.z + qp_l[r * 4 + 3] * k.w;
        }
        sc[t] = acc * SCALE_;
    }
    __syncthreads();

    float m = -1e30f;
    for (int t = tid; t < S_; t += 256) m = fmaxf(m, sc[t]);
    red[tid] = m; __syncthreads();
    for (int st = 128; st > 0; st >>= 1) {
        if (tid < st) red[tid] = fmaxf(red[tid], red[tid + st]);
        __syncthreads();
    }
    m = red[0];
    __syncthreads();

    float sum = 0.f;
    for (int t = tid; t < S_; t += 256) {
        float e = __expf(sc[t] - m);
        sc[t] = e;
        sum += e;
    }
    red[tid] = sum; __syncthreads();
    for (int st = 128; st > 0; st >>= 1) {
        if (tid < st) red[tid] += red[tid + st];
        __syncthreads();
    }
    const float inv = 1.f / red[0];
    __syncthreads();
    for (int t = tid; t < S_; t += 256) sc[t] *= inv;
    __syncthreads();

    float* o_row = qabs_o + row * 512;
    for (int c = tid; c < 512; c += 256) {
        float acc = 0.f;
        const float* kv = kvf + (long)t0 * 576 + c;
        for (int t = 0; t < S_; t++) acc += sc[t] * kv[(long)t * 576];
        o_row[c] = acc;
    }
}

// ---------------------------------------------------------------------------
// Gate: logits -> softmax -> top2 on (probs + gate_b), weights = probs[idx]
// ---------------------------------------------------------------------------
__global__ __launch_bounds__(256) void gate_kernel(
    const float* __restrict__ h2, const float* __restrict__ gw,
    const float* __restrict__ gb, int* __restrict__ idx,
    float* __restrict__ wts)
{
    const int t = blockIdx.x;
    __shared__ float red[256];
    __shared__ float logits[16];
    const int tid = threadIdx.x;
    const int e = tid >> 4, lane = tid & 15;
    const float* x = h2 + (long)t * 2048;
    float s = 0.f;
    for (int i = lane; i < 2048; i += 16) s += x[i] * gw[e * 2048 + i];
    red[tid] = s; __syncthreads();
    for (int st = 8; st > 0; st >>= 1) {
        if (lane < st) red[tid] += red[tid + st];
        __syncthreads();
    }
    if (lane == 0) logits[e] = red[e * 16] + gb[e];
    __syncthreads();
    if (tid == 0) {
        float m = logits[0];
        for (int j = 1; j < 16; j++) m = fmaxf(m, logits[j]);
        float pr[16]; float sum = 0.f;
        for (int j = 0; j < 16; j++) { pr[j] = expf(logits[j] - m); sum += pr[j]; }
        float inv = 1.f / sum;
        for (int j = 0; j < 16; j++) pr[j] *= inv;
        int i1 = 0; float v1 = -1e30f;
        for (int j = 0; j < 16; j++) { float v = pr[j] + gb[j]; if (v > v1) { v1 = v; i1 = j; } }
        int i2 = 0; float v2 = -1e30f;
        for (int j = 0; j < 16; j++) { if (j == i1) continue; float v = pr[j] + gb[j]; if (v > v2) { v2 = v; i2 = j; } }
        idx[t * 2 + 0] = i1; idx[t * 2 + 1] = i2;
        wts[t * 2 + 0] = pr[i1]; wts[t * 2 + 1] = pr[i2];
    }
}

// ---------------------------------------------------------------------------
// Route: sort the 2T (token, k) assignments by expert (counting sort).
// slot_te[pos*2] = (t<<1)|k ; slot_te[pos*2+1] = e ; slot_w[pos] = weight
// ---------------------------------------------------------------------------
__global__ __launch_bounds__(256) void route_kernel(
    const int* __restrict__ idx, const float* __restrict__ wts,
    int* __restrict__ slot_te, float* __restrict__ slot_w)
{
    __shared__ int counts[16], offs[16], cursor[16];
    const int tid = threadIdx.x;
    if (tid < 16) { counts[tid] = 0; cursor[tid] = 0; }
    __syncthreads();
    for (int a = tid; a < 2 * T_; a += 256) atomicAdd(&counts[idx[a]], 1);
    __syncthreads();
    if (tid == 0) {
        int o = 0;
        for (int e = 0; e < 16; e++) { offs[e] = o; o += counts[e]; }
    }
    __syncthreads();
    for (int a = tid; a < 2 * T_; a += 256) {
        int e = idx[a];
        int pos = offs[e] + atomicAdd(&cursor[e], 1);
        int t = a >> 1, k = a & 1;
        slot_te[pos * 2 + 0] = (t << 1) | k;
        slot_te[pos * 2 + 1] = e;
        slot_w[pos] = wts[a];
    }
}

// ---------------------------------------------------------------------------
// MoE expert: one block per routed slot. y_part[k] gets w*(expert(h2)+b2).
// ---------------------------------------------------------------------------
__global__ __launch_bounds__(256) void moe_kernel(
    const float* __restrict__ h2,
    const int* __restrict__ slot_te, const float* __restrict__ slot_w,
    const float* __restrict__ w1, const float* __restrict__ b1,
    const float* __restrict__ w2, const float* __restrict__ b2,
    const float* __restrict__ w3, const float* __restrict__ b3,
    float* __restrict__ y0, float* __restrict__ y1)
{
    const int slot = blockIdx.x;
    const int tk = slot_te[slot * 2 + 0];
    const int e  = slot_te[slot * 2 + 1];
    const int t = tk >> 1, k = tk & 1;
    const float wgt = slot_w[slot];

    __shared__ float xl[2048];
    __shared__ float g[1408];
    const int tid = threadIdx.x;
    const float* x = h2 + (long)t * 2048;
    for (int i = tid; i < 2048; i += 256) xl[i] = x[i];
    __syncthreads();

    const float* W1 = w1 + (long)e * MI_ * 2048;
    const float* W3 = w3 + (long)e * MI_ * 2048;
    for (int i = tid; i < MI_; i += 256) {
        const float4* r1 = (const float4*)(W1 + (long)i * 2048);
        const float4* r3 = (const float4*)(W3 + (long)i * 2048);
        float a = 0.f, b = 0.f;
        for (int c = 0; c < 512; c++) {
            float4 v1 = r1[c], v3 = r3[c];
            float x0 = xl[c * 4 + 0], x1 = xl[c * 4 + 1];
            float x2 = xl[c * 4 + 2], x3 = xl[c * 4 + 3];
            a += v1.x * x0 + v1.y * x1 + v1.z * x2 + v1.w * x3;
            b += v3.x * x0 + v3.y * x1 + v3.z * x2 + v3.w * x3;
        }
        a += b1[e * MI_ + i];
        b += b3[e * MI_ + i];
        g[i] = (a / (1.f + expf(-a))) * b;
    }
    __syncthreads();

    const float* W2 = w2 + (long)e * 2048 * MI_;
    float* y = (k == 0 ? y0 : y1) + (long)t * 2048;
    for (int d = tid; d < 2048; d += 256) {
        const float4* r2 = (const float4*)(W2 + (long)d * MI_);
        float acc = 0.f;
        for (int c = 0; c < MI_ / 4; c++) {
            float4 v = r2[c];
            acc += v.x * g[c * 4 + 0] + v.y * g[c * 4 + 1] +
                   v.z * g[c * 4 + 2] + v.w * g[c * 4 + 3];
        }
        y[d] = wgt * (acc + b2[e * 2048 + d]);
    }
}

// ---------------------------------------------------------------------------
// u1 = silu(u1) * u3
// ---------------------------------------------------------------------------
__global__ void silu_mul_kernel(float* __restrict__ u1,
                                const float* __restrict__ u3, long n)
{
    long i = (long)blockIdx.x * 256 + threadIdx.x;
    if (i >= n) return;
    float a = u1[i];
    u1[i] = (a / (1.f + expf(-a))) * u3[i];
}

// ---------------------------------------------------------------------------
// out = x2 + h2 + y0 + y1 + z
// ---------------------------------------------------------------------------
__global__ void final_add_kernel(const float* __restrict__ x2,
                                 const float* __restrict__ h2,
                                 const float* __restrict__ y0,
                                 const float* __restrict__ y1,
                                 const float* __restrict__ z,
                                 float* __restrict__ out, long n)
{
    long i = (long)blockIdx.x * 256 + threadIdx.x;
    if (i >= n) return;
    out[i] = x2[i] + h2[i] + y0[i] + y1[i] + z[i];
}

// ---------------------------------------------------------------------------
extern "C" void kernel_launch(void* const* d_in, const int* in_sizes, int n_in,
                              void* d_out, int out_size, void* d_ws, size_t ws_size,
                              hipStream_t stream)
{
    (void)in_sizes; (void)n_in; (void)out_size; (void)ws_size;

    const float* x          = (const float*)d_in[0];
    const float* attn_nw    = (const float*)d_in[1];
    const float* ffn_nw     = (const float*)d_in[2];
    const float* wq_a_w     = (const float*)d_in[3];
    const float* wq_a_b     = (const float*)d_in[4];
    const float* q_norm_w   = (const float*)d_in[5];
    const float* wq_b_w     = (const float*)d_in[6];
    const float* wq_b_b     = (const float*)d_in[7];
    const float* wkv_a_w    = (const float*)d_in[8];
    const float* wkv_a_b    = (const float*)d_in[9];
    const float* kv_norm_w  = (const float*)d_in[10];
    const float* wkv_b_w    = (const float*)d_in[11];
    const float* wo_w       = (const float*)d_in[12];
    const float* wo_b       = (const float*)d_in[13];
    const float* gate_w     = (const float*)d_in[14];
    const float* gate_b     = (const float*)d_in[15];
    const float* e_w1       = (const float*)d_in[16];
    const float* e_b1       = (const float*)d_in[17];
    const float* e_w2       = (const float*)d_in[18];
    const float* e_b2       = (const float*)d_in[19];
    const float* e_w3       = (const float*)d_in[20];
    const float* e_b3       = (const float*)d_in[21];
    const float* s_w1       = (const float*)d_in[22];
    const float* s_b1       = (const float*)d_in[23];
    const float* s_w2       = (const float*)d_in[24];
    const float* s_b2       = (const float*)d_in[25];
    const float* s_w3       = (const float*)d_in[26];
    const float* s_b3       = (const float*)d_in[27];
    const float* cosb       = (const float*)d_in[28];
    const float* sinb       = (const float*)d_in[29];

    float* ws = (float*)d_ws;
    // Workspace layout (floats)
    float* h    = ws + 0;            // T*2048          (reused later as y0)
    float* qa   = ws + 4194304;      // T*1536
    float* q    = ws + 7340032;      // T*3072          (reused later as y1)
    float* kvf  = ws + 13631488;     // T*576
    float* qabs = ws + 14811136;     // T*H*512 = 16.8M (q_abs, then o)
    float* o2   = ws + 31588352;     // T*2048
    float* x2   = ws + 35782656;     // T*2048
    float* h2   = ws + 39976960;     // T*2048
    float* u1   = ws + 44171264;     // T*2816
    float* u3   = ws + 49938432;     // T*2816          (reused later as z)
    float* wts  = ws + 55705600;     // T*2 floats
    int*   idx  = (int*)(ws + 55709696);     // T*2 ints
    int*   slot_te = (int*)(ws + 55713792);  // 2T*2 ints
    float* slot_w  = ws + 55721984;          // 2T floats
    float* y0 = h;
    float* y1 = q;
    float* z  = u3;

    // 1. h = rms(x, attn_norm_w)
    rms_kernel<<<dim3(T_), 256, 0, stream>>>(x, h, attn_nw, 2048, 2048, 2048);

    // 2. qa = h @ wq_a_w^T + wq_a_b            [T,1536]
    gemm_kernel<<<dim3(QLR_ / 64, T_ / 64, 1), 256, 0, stream>>>(
        h, 2048, 0, wq_a_w, 2048, 0, 0, wq_a_b, 0,
        nullptr, 0, 0, qa, QLR_, 0, T_, QLR_, 2048);

    // 3. qa = rms(qa, q_norm_w) in place
    rms_kernel<<<dim3(T_), 256, 0, stream>>>(qa, qa, q_norm_w, QLR_, QLR_, QLR_);

    // 4. q = qa @ wq_b_w^T + wq_b_b            [T, 3072]
    gemm_kernel<<<dim3(H_ * QKD_ / 64, T_ / 64, 1), 256, 0, stream>>>(
        qa, QLR_, 0, wq_b_w, QLR_, 0, 0, wq_b_b, 0,
        nullptr, 0, 0, q, H_ * QKD_, 0, T_, H_ * QKD_, QLR_);

    // 5. kvf = h @ wkv_a_w^T + wkv_a_b         [T, 576]
    gemm_kernel<<<dim3((KVR_ + ROPE_) / 64, T_ / 64, 1), 256, 0, stream>>>(
        h, 2048, 0, wkv_a_w, 2048, 0, 0, wkv_a_b, 0,
        nullptr, 0, 0, kvf, KVR_ + ROPE_, 0, T_, KVR_ + ROPE_, 2048);

    // 6. RoPE on q_pe (in q) and k_pe (in kvf), in place
    {
        int total_q = T_ * H_ * 32;
        rope_kernel<<<dim3((total_q + 255) / 256), 256, 0, stream>>>(
            q, cosb, sinb, H_, H_ * QKD_, QKD_, NOPE_, total_q);
        int total_k = T_ * 32;
        rope_kernel<<<dim3((total_k + 255) / 256), 256, 0, stream>>>(
            kvf, cosb, sinb, 1, KVR_ + ROPE_, 0, KVR_, total_k);
    }

    // 7. kv_n = rms(kv, kv_norm_w) in place in kvf[:, :512]
    rms_kernel<<<dim3(T_), 256, 0, stream>>>(kvf, kvf, kv_norm_w, KVR_,
                                             KVR_ + ROPE_, KVR_ + ROPE_);

    // 8. q_abs[t,h,:] = q_nope[t,h,:] @ wb1[h]   (wb1 = wkv_b_w rows h*256..+127, [128,512] K-major)
    gemm_kernel<<<dim3(KVR_ / 64, T_ / 64, H_), 256, 0, stream>>>(
        q, H_ * QKD_, QKD_,                 // A: q_nope per head (lda 3072, head stride 192)
        wkv_b_w, KVR_, (long)256 * KVR_, 1, // W: [K=128, N=512] per head
        nullptr, 0, nullptr, 0, 0,
        qabs, H_ * KVR_, KVR_, T_, KVR_, NOPE_);

    // 9. attention (q_abs -> o, same buffer)
    attn_kernel<<<dim3(S_, H_, B_), 256, 0, stream>>>(q, kvf, qabs);

    // 10. o2[t,h,:] = o[t,h,:] @ wb2[h]^T   (wb2 = rows h*256+128..+255, [128,512])
    gemm_kernel<<<dim3(VD_ / 64, T_ / 64, H_), 256, 0, stream>>>(
        qabs, H_ * KVR_, KVR_,
        wkv_b_w + (long)NOPE_ * KVR_, KVR_, (long)256 * KVR_, 0,
        nullptr, 0, nullptr, 0, 0,
        o2, H_ * VD_, VD_, T_, VD_, KVR_);

    // 11. x2 = x + o2 @ wo_w^T + wo_b
    gemm_kernel<<<dim3(D_ / 64, T_ / 64, 1), 256, 0, stream>>>(
        o2, 2048, 0, wo_w, 2048, 0, 0, wo_b, 0,
        x, 2048, 0, x2, 2048, 0, T_, D_, 2048);

    // 12. h2 = rms(x2, ffn_norm_w)
    rms_kernel<<<dim3(T_), 256, 0, stream>>>(x2, h2, ffn_nw, 2048, 2048, 2048);

    // 13. gate -> top2
    gate_kernel<<<dim3(T_), 256, 0, stream>>>(h2, gate_w, gate_b, idx, wts);

    // 14. route (counting sort by expert)
    route_kernel<<<dim3(1), 256, 0, stream>>>(idx, wts, slot_te, slot_w);

    // 15. MoE experts (one block per slot; slots sorted by expert)
    moe_kernel<<<dim3(2 * T_), 256, 0, stream>>>(
        h2, slot_te, slot_w, e_w1, e_b1, e_w2, e_b2, e_w3, e_b3, y0, y1);

    // 16. shared MLP
    gemm_kernel<<<dim3(SMI_ / 64, T_ / 64, 1), 256, 0, stream>>>(
        h2, 2048, 0, s_w1, 2048, 0, 0, s_b1, 0,
        nullptr, 0, 0, u1, SMI_, 0, T_, SMI_, 2048);
    gemm_kernel<<<dim3(SMI_ / 64, T_ / 64, 1), 256, 0, stream>>>(
        h2, 2048, 0, s_w3, 2048, 0, 0, s_b3, 0,
        nullptr, 0, 0, u3, SMI_, 0, T_, SMI_, 2048);
    {
        long n = (long)T_ * SMI_;
        silu_mul_kernel<<<dim3((unsigned)((n + 255) / 256)), 256, 0, stream>>>(u1, u3, n);
    }
    gemm_kernel<<<dim3(D_ / 64, T_ / 64, 1), 256, 0, stream>>>(
        u1, SMI_, 0, s_w2, SMI_, 0, 0, s_b2, 0,
        nullptr, 0, 0, z, D_, 0, T_, D_, SMI_);

    // 17. out = x2 + h2 + y0 + y1 + z
    {
        long n = (long)T_ * D_;
        final_add_kernel<<<dim3((unsigned)((n + 255) / 256)), 256, 0, stream>>>(
            x2, h2, y0, y1, z, (float*)d_out, n);
    }
}